// Round 6
// baseline (166.518 us; speedup 1.0000x reference)
//
#include <hip/hip_runtime.h>
#include <math.h>

// GMM sufficient statistics + energy, MI355X (gfx950), bf16 MFMA path.
//
// Pipeline (4 dispatches):
//   prep    : f32->bf16 convert + transpose + per-block s1/gamma partials
//   stats   : SYRK via mfma_f32_16x16x32_bf16 (cvt_pk repack)
//   cholinv : sum partials, assemble sigma, register Cholesky + L^-1
//   energy  : V = Z U^T via MFMA, online logsumexp.

#define NR 65536
#define NCOMP 16
#define DDIM 64
#define JITTER 1e-6f
#define LOG2PI 1.83787706640934548356f  // ln(2*pi)

typedef float f32x4 __attribute__((ext_vector_type(4)));
typedef short s16x8 __attribute__((ext_vector_type(8)));
typedef unsigned short u16x4 __attribute__((ext_vector_type(4)));

// ws layout (bytes)
#define OFF_ZBF 0ul            // z bf16 row-major [N][64]            : 8 MiB
#define OFF_ZT  (8ul << 20)    // z bf16 transposed [64][N]           : 8 MiB
#define OFF_SG  (16ul << 20)   // sqrt(gamma) bf16 transposed [16][N] : 2 MiB
#define OFF_S2P (18ul << 20)   // S2 partials f32 [32][16][4096]      : 8 MiB
#define OFF_S1P (26ul << 20)   // s1/gsum partials f32 [1040][256]    : ~1 MiB
#define OFF_UBF (27ul << 20)   // U bf16 [16][64][64]                 : 128 KiB
#define OFF_F32 (28ul << 20)   // tvecT[1024], constk[16]

__device__ __forceinline__ float b2f(unsigned short u) {
  return __uint_as_float(((unsigned)u) << 16);
}
__device__ __forceinline__ unsigned short f2bs(float f) {
  unsigned u = __float_as_uint(f);
  return (unsigned short)((u + 0x7fffu + ((u >> 16) & 1u)) >> 16);
}

// ---------------------------------------------------------------- prep -----
// 256 blocks x 256 threads; block handles 256 rows. No atomics: per-block
// partials for s1/gsum go to s1p[entry][block] (coalesced consumer reads).
__global__ __launch_bounds__(256) void prep_kernel(
    const float* __restrict__ z, const float* __restrict__ gamma,
    unsigned short* __restrict__ zbf, unsigned short* __restrict__ ztbf,
    unsigned short* __restrict__ sgbf, float* __restrict__ s1p) {
  __shared__ unsigned short zt[256][64];  // bf16 copy of tile
  __shared__ float gt[256][16];
  __shared__ float red[16][16];
  const int t = threadIdx.x;
  const int bid = blockIdx.x;
  const long base = (long)bid * 256;

  const float4* z4 = (const float4*)(z + base * 64);
  for (int i = t; i < 4096; i += 256) {
    float4 v = z4[i];
    u16x4 o;
    o[0] = f2bs(v.x); o[1] = f2bs(v.y); o[2] = f2bs(v.z); o[3] = f2bs(v.w);
    int r = i >> 4, c = (i & 15) * 4;
    zt[r][c] = o[0]; zt[r][c + 1] = o[1]; zt[r][c + 2] = o[2]; zt[r][c + 3] = o[3];
    *(u16x4*)(zbf + base * 64 + (long)i * 4) = o;
  }
  const float4* g4 = (const float4*)(gamma + base * 16);
  for (int i = t; i < 1024; i += 256) {
    float4 v = g4[i];
    int r = i >> 2, c = (i & 3) * 4;
    gt[r][c] = v.x; gt[r][c + 1] = v.y; gt[r][c + 2] = v.z; gt[r][c + 3] = v.w;
  }
  __syncthreads();

  // transposed z (bf16): ZT[l][r]
  {
    int l = t >> 2, rp = t & 3;
    for (int j8 = 0; j8 < 64; j8 += 8) {
      s16x8 o;
#pragma unroll
      for (int u2 = 0; u2 < 8; ++u2) o[u2] = (short)zt[rp * 64 + j8 + u2][l];
      *(s16x8*)(ztbf + (long)l * NR + base + rp * 64 + j8) = o;
    }
  }
  // transposed sqrt(gamma) (bf16): SG[k][r]
  if (t < 128) {
    int k = t >> 3, rp = t & 7;
    for (int j8 = 0; j8 < 32; j8 += 8) {
      s16x8 o;
#pragma unroll
      for (int u2 = 0; u2 < 8; ++u2)
        o[u2] = (short)f2bs(sqrtf(gt[rp * 32 + j8 + u2][k]));
      *(s16x8*)(sgbf + (long)k * NR + base + rp * 32 + j8) = o;
    }
  }
  // gamma_sum block partial (fp32 exact)
  {
    int k = t & 15, rp = t >> 4;
    float s = 0.f;
#pragma unroll
    for (int j = 0; j < 16; ++j) s += gt[rp * 16 + j][k];
    red[k][rp] = s;
  }
  __syncthreads();
  if (t < 16) {
    float s = 0.f;
#pragma unroll
    for (int c = 0; c < 16; ++c) s += red[t][c];
    s1p[(1024 + t) * 256 + bid] = s;
  }
  // S1 block partial: S1[k][l] = sum_r gamma[r][k] * z[r][l]
  {
    int l = t & 63, kq = t >> 6;
    float a0 = 0.f, a1 = 0.f, a2 = 0.f, a3 = 0.f;
    for (int r = 0; r < 256; ++r) {
      float zv = b2f(zt[r][l]);
      const float4 gv = *(const float4*)&gt[r][kq * 4];
      a0 = fmaf(gv.x, zv, a0); a1 = fmaf(gv.y, zv, a1);
      a2 = fmaf(gv.z, zv, a2); a3 = fmaf(gv.w, zv, a3);
    }
    s1p[((kq * 4 + 0) * 64 + l) * 256 + bid] = a0;
    s1p[((kq * 4 + 1) * 64 + l) * 256 + bid] = a1;
    s1p[((kq * 4 + 2) * 64 + l) * 256 + bid] = a2;
    s1p[((kq * 4 + 3) * 64 + l) * 256 + bid] = a3;
  }
}

// --------------------------------------------------------------- stats -----
// 512 blocks (32 row-chunks x 16 components, XCD-swizzled) x 256 threads.
// Repack sqrt(gamma)*z in bf16 pairs: u32 unpack + 2 mul + v_cvt_pk_bf16_f32.
__global__ __launch_bounds__(256) void stats_kernel(
    const unsigned short* __restrict__ ztbf,
    const unsigned short* __restrict__ sgbf, float* __restrict__ s2p) {
  __shared__ float s2w[4][4096];
  const int t = threadIdx.x;
  const int bid = blockIdx.x;
  const int xcd = bid & 7, gi = bid >> 3;
  const int chunk = xcd * 4 + (gi & 3);  // 0..31
  const int comp = gi >> 2;              // 0..15
  const int w = t >> 6, la = t & 15, hi = (t & 63) >> 4;
  const long rbase = (long)chunk * 2048 + w * 512;
  f32x4 acc[4][4];
#pragma unroll
  for (int a = 0; a < 4; ++a)
#pragma unroll
    for (int b2 = 0; b2 < 4; ++b2) acc[a][b2] = (f32x4){0.f, 0.f, 0.f, 0.f};

  for (int ks = 0; ks < 16; ++ks) {
    const long r0 = rbase + ks * 32 + hi * 8;
    const uint4 sg4 = *(const uint4*)(sgbf + (long)comp * NR + r0);
    const unsigned sgu[4] = {sg4.x, sg4.y, sg4.z, sg4.w};
    float gl[4], gh[4];
#pragma unroll
    for (int p = 0; p < 4; ++p) {
      gl[p] = __uint_as_float(sgu[p] << 16);
      gh[p] = __uint_as_float(sgu[p] & 0xffff0000u);
    }
    s16x8 sq[4];
#pragma unroll
    for (int T = 0; T < 4; ++T) {
      const uint4 zv = *(const uint4*)(ztbf + (long)(T * 16 + la) * NR + r0);
      const unsigned zu[4] = {zv.x, zv.y, zv.z, zv.w};
      unsigned rr[4];
#pragma unroll
      for (int p = 0; p < 4; ++p) {
        const float pl = __uint_as_float(zu[p] << 16) * gl[p];
        const float ph = __uint_as_float(zu[p] & 0xffff0000u) * gh[p];
        asm("v_cvt_pk_bf16_f32 %0, %1, %2" : "=v"(rr[p]) : "v"(pl), "v"(ph));
      }
      sq[T] = __builtin_bit_cast(s16x8, make_uint4(rr[0], rr[1], rr[2], rr[3]));
    }
#pragma unroll
    for (int a = 0; a < 4; ++a)
#pragma unroll
      for (int b2 = 0; b2 < 4; ++b2)
        acc[a][b2] = __builtin_amdgcn_mfma_f32_16x16x32_bf16(sq[a], sq[b2],
                                                             acc[a][b2], 0, 0, 0);
  }
  // C/D layout: col = lane&15, row = (lane>>4)*4 + reg (HW-verified)
#pragma unroll
  for (int a = 0; a < 4; ++a)
#pragma unroll
    for (int b2 = 0; b2 < 4; ++b2)
#pragma unroll
      for (int rg = 0; rg < 4; ++rg)
        s2w[w][(a * 16 + hi * 4 + rg) * 64 + b2 * 16 + la] = acc[a][b2][rg];
  __syncthreads();
  float* outp = s2p + ((long)chunk * NCOMP + comp) * 4096;
  for (int i = t; i < 4096; i += 256)
    outp[i] = (s2w[0][i] + s2w[1][i]) + (s2w[2][i] + s2w[3][i]);
}

// -------------------------------------------------------------- cholinv ----
// 16 blocks x 256 threads. Phase 1: sum s1/gsum partials, assemble sigma in
// LDS (absorbs the old reduce kernel). Phase 2 (wave 0): fused register-only
// Cholesky + forward substitution via static-lane readlane broadcasts.
__global__ __launch_bounds__(256) void cholinv_kernel(
    const float* __restrict__ s2p, const float* __restrict__ s1p,
    unsigned short* __restrict__ ubf, float* __restrict__ tvecT,
    float* __restrict__ constk) {
  __shared__ float sig[64][65];
  __shared__ float Ut[64][66];
  __shared__ float part[4][64];
  __shared__ float gred[4];
  __shared__ float mu_s[64];
  const int t = threadIdx.x, k = blockIdx.x;
  const int l = t & 63, q = t >> 6;

  // gamma_sum: 256 partials, coalesced + wave reduce
  float gp = s1p[(1024 + k) * 256 + t];
#pragma unroll
  for (int off = 32; off; off >>= 1) gp += __shfl_xor(gp, off);
  if (l == 0) gred[q] = gp;
  // s1: lane (q,l) sums its 64-block range (16 x float4)
  {
    const float4* rowp = (const float4*)(s1p + (k * 64 + l) * 256 + q * 64);
    float4 s4 = {0.f, 0.f, 0.f, 0.f};
#pragma unroll
    for (int b = 0; b < 16; ++b) {
      const float4 v = rowp[b];
      s4.x += v.x; s4.y += v.y; s4.z += v.z; s4.w += v.w;
    }
    part[q][l] = (s4.x + s4.y) + (s4.z + s4.w);
  }
  __syncthreads();
  const float gs = (gred[0] + gred[1]) + (gred[2] + gred[3]);
  if (t < 64)
    mu_s[t] = ((part[0][t] + part[1][t]) + (part[2][t] + part[3][t])) / gs;
  __syncthreads();

  // sigma = S2/gs - mu mu^T + jitter I  (1024 float4 slots)
  const float ginv = 1.f / gs;
  for (int s = t; s < 1024; s += 256) {
    float4 a4 = {0.f, 0.f, 0.f, 0.f};
#pragma unroll 8
    for (int c = 0; c < 32; ++c) {
      const float4 v = *(const float4*)(s2p + ((long)c * NCOMP + k) * 4096 + s * 4);
      a4.x += v.x; a4.y += v.y; a4.z += v.z; a4.w += v.w;
    }
    const int a = s >> 4, b0 = (s & 15) * 4;
    const float ma = mu_s[a];
    sig[a][b0 + 0] = a4.x * ginv - ma * mu_s[b0 + 0] + ((a == b0 + 0) ? JITTER : 0.f);
    sig[a][b0 + 1] = a4.y * ginv - ma * mu_s[b0 + 1] + ((a == b0 + 1) ? JITTER : 0.f);
    sig[a][b0 + 2] = a4.z * ginv - ma * mu_s[b0 + 2] + ((a == b0 + 2) ? JITTER : 0.f);
    sig[a][b0 + 3] = a4.w * ginv - ma * mu_s[b0 + 3] + ((a == b0 + 3) ? JITTER : 0.f);
  }
  __syncthreads();

  if (t < 64) {  // wave 0: register Cholesky + L^-1 (lane c owns column c)
    const int c = t;
    float col[64], lr[64], ux[64];
#pragma unroll
    for (int m = 0; m < 64; ++m) col[m] = sig[m][c];

    float ld = 0.f;
#pragma unroll
    for (int j = 0; j < 64; ++j) {
      float cj = col[j];
      float ax = 0.f;
#pragma unroll
      for (int jp = 0; jp < j; ++jp) {
        const float b = __uint_as_float(
            __builtin_amdgcn_readlane(__float_as_uint(lr[jp]), j));  // L[j][jp]
        cj = fmaf(-b, lr[jp], cj);
        ax = fmaf(-b, ux[jp], ax);
      }
      const float p = __uint_as_float(
          __builtin_amdgcn_readlane(__float_as_uint(cj), j));  // pivot L_jj^2
      const float dinv = rsqrtf(p);
      ld += __log2f(p);
      lr[j] = cj * dinv;
      ux[j] = (((c == j) ? 1.f : 0.f) + ax) * dinv;
    }
#pragma unroll
    for (int j = 0; j < 64; ++j) Ut[j][c] = b2f(f2bs(ux[j]));  // rounded
    if (c == 0)
      constk[k] = logf(gs / (float)NR) + 64.f * LOG2PI
                  + 0.69314718055994530942f * ld;
  }
  __syncthreads();
  // U bf16 out (coalesced), by all 256 threads; values already representable
  for (int idx = t; idx < 4096; idx += 256)
    ubf[k * 4096 + idx] = f2bs(Ut[idx >> 6][idx & 63]);
  // tvecT[k][la*4+mt] = U_bf16 row (mt*16+la) . mu   (float4-loadable)
  if (t < 64) {
    float s = 0.f;
#pragma unroll
    for (int l2 = 0; l2 < 64; ++l2) s = fmaf(Ut[t][l2], mu_s[l2], s);
    tvecT[k * 64 + (t & 15) * 4 + (t >> 4)] = s;
  }
}

// --------------------------------------------------------------- energy ----
// 512 blocks x 256 threads; block = 128 rows, wave = 32 rows. No LDS.
// za fragments hoisted out of the comp loop; tvec loads as one float4/comp.
__global__ __launch_bounds__(256) void energy_kernel(
    const unsigned short* __restrict__ zbf, const unsigned short* __restrict__ ubf,
    const float* __restrict__ tvecT, const float* __restrict__ constk,
    float* __restrict__ out) {
  const int t = threadIdx.x;
  const int w = t >> 6, la = t & 15, hi = (t & 63) >> 4;
  const long r0 = (long)blockIdx.x * 128 + w * 32;

  s16x8 za[2][2];  // [rs][ks], comp-invariant
#pragma unroll
  for (int rs = 0; rs < 2; ++rs)
#pragma unroll
    for (int ks = 0; ks < 2; ++ks)
      za[rs][ks] = *(const s16x8*)(zbf + (r0 + rs * 16 + la) * 64 + ks * 32 + hi * 8);

  float M[2][4], S[2][4];
#pragma unroll
  for (int rs = 0; rs < 2; ++rs)
#pragma unroll
    for (int rg = 0; rg < 4; ++rg) { M[rs][rg] = -3.0e38f; S[rs][rg] = 0.f; }

  for (int comp = 0; comp < NCOMP; ++comp) {
    const float4 tv4 = ((const float4*)tvecT)[comp * 16 + la];
    const float tvv[4] = {tv4.x, tv4.y, tv4.z, tv4.w};
    const float cst = constk[comp];
    f32x4 acc[2][4];
#pragma unroll
    for (int rs = 0; rs < 2; ++rs)
#pragma unroll
      for (int mt = 0; mt < 4; ++mt) acc[rs][mt] = (f32x4){0.f, 0.f, 0.f, 0.f};
#pragma unroll
    for (int ks = 0; ks < 2; ++ks) {
      const int l0 = ks * 32 + hi * 8;
      s16x8 ub[4];
#pragma unroll
      for (int mt = 0; mt < 4; ++mt)
        ub[mt] = *(const s16x8*)(ubf + ((long)comp * 64 + mt * 16 + la) * 64 + l0);
#pragma unroll
      for (int rs = 0; rs < 2; ++rs)
#pragma unroll
        for (int mt = 0; mt < 4; ++mt)
          acc[rs][mt] = __builtin_amdgcn_mfma_f32_16x16x32_bf16(za[rs][ks], ub[mt],
                                                                acc[rs][mt], 0, 0, 0);
    }
    // q = sum_m (V[r][m] - t_m)^2 ; reduce across the 16-lane column group
#pragma unroll
    for (int rs = 0; rs < 2; ++rs)
#pragma unroll
      for (int rg = 0; rg < 4; ++rg) {
        float qv = 0.f;
#pragma unroll
        for (int mt = 0; mt < 4; ++mt) {
          float d0 = acc[rs][mt][rg] - tvv[mt];
          qv = fmaf(d0, d0, qv);
        }
        qv += __shfl_xor(qv, 1);
        qv += __shfl_xor(qv, 2);
        qv += __shfl_xor(qv, 4);
        qv += __shfl_xor(qv, 8);
        float lg = cst - 0.5f * qv;
        float Mn = fmaxf(M[rs][rg], lg);
        S[rs][rg] = S[rs][rg] * __expf(M[rs][rg] - Mn) + __expf(lg - Mn);
        M[rs][rg] = Mn;
      }
  }
  if (la == 0) {
#pragma unroll
    for (int rs = 0; rs < 2; ++rs)
#pragma unroll
      for (int rg = 0; rg < 4; ++rg)
        out[r0 + rs * 16 + hi * 4 + rg] = -(M[rs][rg] + __logf(S[rs][rg]));
  }
}

// ---------------------------------------------------------------------------
extern "C" void kernel_launch(void* const* d_in, const int* in_sizes, int n_in,
                              void* d_out, int out_size, void* d_ws, size_t ws_size,
                              hipStream_t stream) {
  const float* z = (const float*)d_in[0];
  const float* gamma = (const float*)d_in[1];
  float* out = (float*)d_out;
  char* ws = (char*)d_ws;
  unsigned short* zbf = (unsigned short*)(ws + OFF_ZBF);
  unsigned short* ztbf = (unsigned short*)(ws + OFF_ZT);
  unsigned short* sgbf = (unsigned short*)(ws + OFF_SG);
  float* s2p = (float*)(ws + OFF_S2P);
  float* s1p = (float*)(ws + OFF_S1P);
  unsigned short* ubf = (unsigned short*)(ws + OFF_UBF);
  float* f32a = (float*)(ws + OFF_F32);
  float* tvecT = f32a;
  float* ck = f32a + 1024;

  hipLaunchKernelGGL(prep_kernel, dim3(256), dim3(256), 0, stream,
                     z, gamma, zbf, ztbf, sgbf, s1p);
  hipLaunchKernelGGL(stats_kernel, dim3(512), dim3(256), 0, stream,
                     ztbf, sgbf, s2p);
  hipLaunchKernelGGL(cholinv_kernel, dim3(16), dim3(256), 0, stream,
                     s2p, s1p, ubf, tvecT, ck);
  hipLaunchKernelGGL(energy_kernel, dim3(512), dim3(256), 0, stream,
                     zbf, ubf, tvecT, ck, out);
}